// Round 6
// baseline (542.379 us; speedup 1.0000x reference)
//
#include <hip/hip_runtime.h>

// LSTM RNN: B=2048, L=256 (257 steps), F=64, H=32, K=2.
// R6: TWO independent 2-row streams per wave (4 batch rows), 512 wgs x 64 thr.
// Rationale: single-stream loop is latency-bound (~40% idle issue slots at
// ~1.2 GHz DPM clock); the second stream's bpermute/MFMA/VALU fills the
// first stream's dependency stalls. Weights (Bf/BLd/Dsel) shared across
// streams; only C0/hw/cst duplicate. Barrier-free loop; h exchange via
// ds_bpermute crossbar; softplus in epilogue from Lbuf; setup parallelized.

typedef __attribute__((ext_vector_type(8))) short bf16x8;
typedef __attribute__((ext_vector_type(4))) float f32x4;
typedef __attribute__((ext_vector_type(4))) unsigned u32x4;

#define L2E 1.44269504088896340736f
#define LN2 0.69314718055994530942f

__device__ __forceinline__ short f2bf(float x) {
    unsigned u = __builtin_bit_cast(unsigned, x);
    unsigned r = (u + 0x7FFFu + ((u >> 16) & 1u)) >> 16;
    return (short)r;
}
__device__ __forceinline__ float fsig(float x) {
    float e = __builtin_amdgcn_exp2f(-L2E * x);
    return __builtin_amdgcn_rcpf(1.0f + e);
}
__device__ __forceinline__ float ftanh(float x) {
    float e = __builtin_amdgcn_exp2f(-2.0f * L2E * x);
    return 2.0f * __builtin_amdgcn_rcpf(1.0f + e) - 1.0f;
}

// ws byte offsets
#define WS_WHT   0          // bf16 [n=256][k=256]  (131072 B)
#define WS_B2T   131072     // bf16 [n=256][k=32]   (16384 B)
#define WS_AMPD  147456     // bf16 [64]            (128 B)
#define WS_C0V   147584     // f32  [256]
#define WS_DSV   148608     // f32  [256]
#define WS_BDF   149632     // f32  [1]

__global__ __launch_bounds__(256) void setup_fold(
    const float* __restrict__ W_emb, const float* __restrict__ b_emb,
    const float* __restrict__ W_g2, const float* __restrict__ b_g2,
    const float* __restrict__ Wi, const float* __restrict__ b_lstm,
    const float* __restrict__ W_amp, const float* __restrict__ b_amp,
    unsigned char* __restrict__ ws)
{
    short* b2T  = (short*)(ws + WS_B2T);
    short* ampd = (short*)(ws + WS_AMPD);
    float* c0v  = (float*)(ws + WS_C0V);
    float* dsv  = (float*)(ws + WS_DSV);
    float* bdf  = (float*)(ws + WS_BDF);

    const int bi = blockIdx.x;
    const int n  = threadIdx.x;   // gate col
    if (bi < 32) {                // b2T row k = bi
        float a = 0.f;
        for (int f = 0; f < 64; ++f)
            a += W_g2[bi * 64 + f] * Wi[f * 256 + n];
        b2T[n * 32 + bi] = f2bf(a);
    } else if (bi == 32) {        // one-hot/bias folds
        float a32 = 0.f, a33 = 0.f, a34 = 0.f;
        for (int f = 0; f < 64; ++f) {
            float wi = Wi[f * 256 + n];
            a32 += W_emb[f] * wi;
            a33 += W_emb[64 + f] * wi;
            a34 += (b_emb[f] + b_g2[f]) * wi;
        }
        c0v[n] = a32 + a34 + b_lstm[n];
        dsv[n] = a33 - a32;
    } else {
        if (n < 64) ampd[n] = f2bf(W_amp[n * 2 + 1] - W_amp[n * 2]);
        if (n == 0) bdf[0] = b_amp[1] - b_amp[0];
    }
}

__global__ __launch_bounds__(256) void setup_tr(
    const float* __restrict__ Wh, unsigned char* __restrict__ ws)
{
    short* whT = (short*)(ws + WS_WHT);
    const int n = blockIdx.x;        // 256 gate cols
    const int k = threadIdx.x;       // 256 k rows
    whT[n * 256 + k] = f2bf(Wh[k * 256 + n]);
}

__global__ __launch_bounds__(64) void lstm_kernel(
    const int* __restrict__ s, const float* __restrict__ g,
    const float* __restrict__ W_g1, const float* __restrict__ b_g1,
    const float* __restrict__ W_gh, const float* __restrict__ b_gh,
    const float* __restrict__ W_gc, const float* __restrict__ b_gc,
    const unsigned char* __restrict__ ws, float* __restrict__ out)
{
    const short* whT  = (const short*)(ws + WS_WHT);
    const short* b2T  = (const short*)(ws + WS_B2T);
    const short* ampd = (const short*)(ws + WS_AMPD);
    const float* c0v  = (const float*)(ws + WS_C0V);
    const float* dsv  = (const float*)(ws + WS_DSV);
    const float* bdf  = (const float*)(ws + WS_BDF);

    __shared__ unsigned char sp_l[264];   // nibble per t: bits b=0..3 of s_pad
    __shared__ float Lbuf[2][257][2];     // per-stream logit diffs

    const int l   = threadIdx.x;   // 64
    const int n2  = l & 15;        // MFMA col / A-row
    const int q   = l >> 4;        // MFMA quad
    const int wgb = blockIdx.x * 4;

    // token staging: sp_l[t] = bits of s[:, t-1]; sp_l[0] = 0; pad to 263
    for (int t = l; t < 264; t += 64) {
        unsigned v = 0;
        if (t >= 1 && t <= 256) {
            v = (unsigned)(s[(wgb + 0) * 256 + t - 1] & 1)
              | ((unsigned)(s[(wgb + 1) * 256 + t - 1] & 1) << 1)
              | ((unsigned)(s[(wgb + 2) * 256 + t - 1] & 1) << 2)
              | ((unsigned)(s[(wgb + 3) * 256 + t - 1] & 1) << 3);
        }
        sp_l[t] = (unsigned char)v;
    }

    // ---------- shared static fragments ----------
    bf16x8 Bf[16][2];
    #pragma unroll
    for (int tb = 0; tb < 16; ++tb) {
        const int n = tb * 16 + n2;
        #pragma unroll
        for (int kf = 0; kf < 2; ++kf)
            Bf[tb][kf] = *(const bf16x8*)(whT + n * 256 + kf * 32 + q * 8);
    }
    bf16x8 BLd0 = {0,0,0,0,0,0,0,0}, BLd1 = {0,0,0,0,0,0,0,0};
    f32x4 CL0 = {0.f, 0.f, 0.f, 0.f};
    if (n2 == 0) {
        BLd0 = *(const bf16x8*)(ampd + q * 8);
        BLd1 = *(const bf16x8*)(ampd + 32 + q * 8);
        float bd = bdf[0];
        CL0[0] = bd; CL0[1] = bd; CL0[2] = bd; CL0[3] = bd;
    }
    float Dsel4[4];
    #pragma unroll
    for (int gi = 0; gi < 4; ++gi) Dsel4[gi] = dsv[gi * 64 + l];

    // ---------- per-stream state ----------
    f32x4 C0[2][16];
    float cst[2][2];
    int hw[2];
    const f32x4 zero4 = {0.f, 0.f, 0.f, 0.f};
    #pragma unroll
    for (int st = 0; st < 2; ++st) {
        const float g_a = g[wgb + st * 2 + (n2 & 1)];
        bf16x8 Atv;
        #pragma unroll
        for (int j = 0; j < 8; ++j) {
            int k = q * 8 + j;
            Atv[j] = f2bf(tanhf(g_a * W_g1[k] + b_g1[k]));
        }
        #pragma unroll
        for (int tb = 0; tb < 16; ++tb) {
            bf16x8 b2f = *(const bf16x8*)(b2T + (tb * 16 + n2) * 32 + q * 8);
            C0[st][tb] = __builtin_amdgcn_mfma_f32_16x16x32_bf16(Atv, b2f, zero4, 0, 0, 0);
            float ca = c0v[tb * 16 + n2];
            #pragma unroll
            for (int r = 0; r < 4; ++r) C0[st][tb][r] += ca;
        }
        float g0 = g[wgb + st * 2 + 0], g1 = g[wgb + st * 2 + 1];
        cst[st][0] = g0 * W_gc[l] + b_gc[l];
        cst[st][1] = g1 * W_gc[l] + b_gc[l];
        unsigned h0 = (unsigned short)f2bf(g0 * W_gh[l] + b_gh[l]);
        unsigned h1 = (unsigned short)f2bf(g1 * W_gh[l] + b_gh[l]);
        hw[st] = (int)(h0 | (h1 << 16));
    }
    __syncthreads();   // sp_l visibility; none in the loop

    // ---------- recurrence: 257 steps, single wave, 2 streams ----------
    const bool mq1 = (q & 1) != 0, mq2 = (q & 2) != 0;
    const int baseA = q * 32;
    const unsigned selv = (n2 & 1) ? 0x07060302u : 0x05040100u;
    unsigned spt = 0;                                       // sp_l[0]

    for (int t = 0; t <= 256; ++t) {
        unsigned spt_n = sp_l[t + 1];      // prefetch, consumed next iter

        // crossbars (both streams; independent LDS-pipe ops)
        bf16x8 a0[2], a1[2];
        #pragma unroll
        for (int st = 0; st < 2; ++st) {
            int pA[8], pB[8];
            #pragma unroll
            for (int j = 0; j < 8; ++j) {
                pA[j] = __builtin_amdgcn_ds_bpermute(baseA + 4 * j, hw[st]);
                pB[j] = __builtin_amdgcn_ds_bpermute(baseA + 128 + 4 * j, hw[st]);
            }
            u32x4 a0u, a1u;
            #pragma unroll
            for (int d = 0; d < 4; ++d) {
                a0u[d] = __builtin_amdgcn_perm((unsigned)pA[2 * d + 1], (unsigned)pA[2 * d], selv);
                a1u[d] = __builtin_amdgcn_perm((unsigned)pB[2 * d + 1], (unsigned)pB[2 * d], selv);
            }
            a0[st] = __builtin_bit_cast(bf16x8, a0u);
            a1[st] = __builtin_bit_cast(bf16x8, a1u);
        }

        // gate MFMAs, streams interleaved per tile
        f32x4 acc[2][16];
        #pragma unroll
        for (int tb = 0; tb < 16; ++tb) {
            #pragma unroll
            for (int st = 0; st < 2; ++st) {
                f32x4 tmp = __builtin_amdgcn_mfma_f32_16x16x32_bf16(
                    a1[st], Bf[tb][1], C0[st][tb], 0, 0, 0);
                acc[st][tb] = __builtin_amdgcn_mfma_f32_16x16x32_bf16(
                    a0[st], Bf[tb][0], tmp, 0, 0, 0);
            }
        }
        // logit diffs
        f32x4 accL[2];
        #pragma unroll
        for (int st = 0; st < 2; ++st) {
            f32x4 tL = __builtin_amdgcn_mfma_f32_16x16x32_bf16(a1[st], BLd1, CL0, 0, 0, 0);
            accL[st] = __builtin_amdgcn_mfma_f32_16x16x32_bf16(a0[st], BLd0, tL, 0, 0, 0);
        }
        if (l == 0) {      // stash logit pairs; softplus in epilogue
            Lbuf[0][t][0] = accL[0][0];
            Lbuf[0][t][1] = accL[0][1];
            Lbuf[1][t][0] = accL[1][0];
            Lbuf[1][t][1] = accL[1][1];
        }

        // extraction + gate math per stream (t=256 computes dead h; harmless)
        #pragma unroll
        for (int st = 0; st < 2; ++st) {
            const float fr0 = (float)((spt >> (st * 2)) & 1u);
            const float fr1 = (float)((spt >> (st * 2 + 1)) & 1u);
            float z[4][2];
            #pragma unroll
            for (int gi = 0; gi < 4; ++gi) {
                #pragma unroll
                for (int b = 0; b < 2; ++b) {
                    float x01 = mq1 ? acc[st][4 * gi + 1][b] : acc[st][4 * gi + 0][b];
                    float x23 = mq1 ? acc[st][4 * gi + 3][b] : acc[st][4 * gi + 2][b];
                    float fr  = b ? fr1 : fr0;
                    z[gi][b] = (mq2 ? x23 : x01) + fr * Dsel4[gi];
                }
            }
            unsigned hparts[2];
            #pragma unroll
            for (int b = 0; b < 2; ++b) {
                float si = fsig(z[0][b]), sf = fsig(z[1][b]);
                float tg = ftanh(z[2][b]), so = fsig(z[3][b]);
                float c = sf * cst[st][b] + si * tg;
                cst[st][b] = c;
                hparts[b] = (unsigned short)f2bf(so * ftanh(c));
            }
            hw[st] = (int)(hparts[0] | (hparts[1] << 16));
        }
        spt = spt_n;
    }

    // ---------- epilogue: softplus + reduce per stream ----------
    __syncthreads();   // drain lane-0 Lbuf writes
    float part[2] = {0.f, 0.f};
    for (int i = l; i < 514; i += 64) {    // i = 2t+b; b = l&1 fixed by parity
        int t = i >> 1, b = i & 1;
        if (t >= 1) {
            unsigned sb = sp_l[t];
            #pragma unroll
            for (int st = 0; st < 2; ++st) {
                float d = Lbuf[st][t][b];
                float x = ((sb >> (st * 2 + b)) & 1u) ? -d : d;   // l_other - l_s
                float e = __builtin_amdgcn_exp2f(L2E * x);
                part[st] -= LN2 * __builtin_amdgcn_logf(1.0f + e);
            }
        }
    }
    #pragma unroll
    for (int m = 2; m <= 32; m <<= 1) {
        part[0] += __shfl_xor(part[0], m);   // parity-preserving reduce
        part[1] += __shfl_xor(part[1], m);
    }
    if (l < 2) {
        out[wgb + l]     = part[0];
        out[wgb + 2 + l] = part[1];
    }
}

extern "C" void kernel_launch(void* const* d_in, const int* in_sizes, int n_in,
                              void* d_out, int out_size, void* d_ws, size_t ws_size,
                              hipStream_t stream) {
    (void)in_sizes; (void)n_in; (void)out_size; (void)ws_size;
    const int*   s      = (const int*)d_in[0];
    const float* g      = (const float*)d_in[1];
    const float* W_emb  = (const float*)d_in[2];
    const float* b_emb  = (const float*)d_in[3];
    const float* W_g1   = (const float*)d_in[4];
    const float* b_g1   = (const float*)d_in[5];
    const float* W_g2   = (const float*)d_in[6];
    const float* b_g2   = (const float*)d_in[7];
    const float* W_gh   = (const float*)d_in[8];
    const float* b_gh   = (const float*)d_in[9];
    const float* W_gc   = (const float*)d_in[10];
    const float* b_gc   = (const float*)d_in[11];
    const float* Wi     = (const float*)d_in[12];
    const float* Wh     = (const float*)d_in[13];
    const float* b_lstm = (const float*)d_in[14];
    const float* W_amp  = (const float*)d_in[15];
    const float* b_amp  = (const float*)d_in[16];
    float* out = (float*)d_out;
    unsigned char* ws = (unsigned char*)d_ws;

    setup_fold<<<34, 256, 0, stream>>>(W_emb, b_emb, W_g2, b_g2, Wi,
                                       b_lstm, W_amp, b_amp, ws);
    setup_tr<<<256, 256, 0, stream>>>(Wh, ws);
    lstm_kernel<<<512, 64, 0, stream>>>(s, g, W_g1, b_g1, W_gh, b_gh,
                                        W_gc, b_gc, ws, out);
}

// Round 7
// 307.161 us; speedup vs baseline: 1.7658x; 1.7658x over previous
//
#include <hip/hip_runtime.h>

// LSTM RNN: B=2048, L=256 (257 steps), F=64, H=32, K=2.
// R7: R4 skeleton (single-wave wgs, barrier-free, bpermute h-crossbar) with
// INDEPENDENT MFMA accumulators: accA[tb]=mfma(a0,B0,C0), accB[tb]=mfma(a1,B1,0)
// summed at extraction. Kills the chained-pair RAW stalls (~40 cyc/pair ->
// ~17 cyc/MFMA pipelined). 1024 wgs x 64 thr, 2 batch rows/wave.
// Weights Bf/C0 are MFMA-only -> AGPRs; accA/accB live ~200 cyc in VGPRs.

typedef __attribute__((ext_vector_type(8))) short bf16x8;
typedef __attribute__((ext_vector_type(4))) float f32x4;
typedef __attribute__((ext_vector_type(4))) unsigned u32x4;

#define L2E 1.44269504088896340736f
#define LN2 0.69314718055994530942f

__device__ __forceinline__ short f2bf(float x) {
    unsigned u = __builtin_bit_cast(unsigned, x);
    unsigned r = (u + 0x7FFFu + ((u >> 16) & 1u)) >> 16;
    return (short)r;
}
__device__ __forceinline__ float fsig(float x) {
    float e = __builtin_amdgcn_exp2f(-L2E * x);
    return __builtin_amdgcn_rcpf(1.0f + e);
}
__device__ __forceinline__ float ftanh(float x) {
    float e = __builtin_amdgcn_exp2f(-2.0f * L2E * x);
    return 2.0f * __builtin_amdgcn_rcpf(1.0f + e) - 1.0f;
}

// ws byte offsets
#define WS_WHT   0          // bf16 [n=256][k=256]  (131072 B)
#define WS_B2T   131072     // bf16 [n=256][k=32]   (16384 B)
#define WS_AMPD  147456     // bf16 [64]            (128 B)
#define WS_C0V   147584     // f32  [256]
#define WS_DSV   148608     // f32  [256]
#define WS_BDF   149632     // f32  [1]

__global__ __launch_bounds__(256) void setup_fold(
    const float* __restrict__ W_emb, const float* __restrict__ b_emb,
    const float* __restrict__ W_g2, const float* __restrict__ b_g2,
    const float* __restrict__ Wi, const float* __restrict__ b_lstm,
    const float* __restrict__ W_amp, const float* __restrict__ b_amp,
    unsigned char* __restrict__ ws)
{
    short* b2T  = (short*)(ws + WS_B2T);
    short* ampd = (short*)(ws + WS_AMPD);
    float* c0v  = (float*)(ws + WS_C0V);
    float* dsv  = (float*)(ws + WS_DSV);
    float* bdf  = (float*)(ws + WS_BDF);

    const int bi = blockIdx.x;
    const int n  = threadIdx.x;   // gate col
    if (bi < 32) {                // b2T row k = bi
        float a = 0.f;
        for (int f = 0; f < 64; ++f)
            a += W_g2[bi * 64 + f] * Wi[f * 256 + n];
        b2T[n * 32 + bi] = f2bf(a);
    } else if (bi == 32) {        // one-hot/bias folds
        float a32 = 0.f, a33 = 0.f, a34 = 0.f;
        for (int f = 0; f < 64; ++f) {
            float wi = Wi[f * 256 + n];
            a32 += W_emb[f] * wi;
            a33 += W_emb[64 + f] * wi;
            a34 += (b_emb[f] + b_g2[f]) * wi;
        }
        c0v[n] = a32 + a34 + b_lstm[n];
        dsv[n] = a33 - a32;
    } else {
        if (n < 64) ampd[n] = f2bf(W_amp[n * 2 + 1] - W_amp[n * 2]);
        if (n == 0) bdf[0] = b_amp[1] - b_amp[0];
    }
}

__global__ __launch_bounds__(256) void setup_tr(
    const float* __restrict__ Wh, unsigned char* __restrict__ ws)
{
    short* whT = (short*)(ws + WS_WHT);
    const int n = blockIdx.x;        // 256 gate cols
    const int k = threadIdx.x;       // 256 k rows
    whT[n * 256 + k] = f2bf(Wh[k * 256 + n]);
}

__global__ __launch_bounds__(64) void lstm_kernel(
    const int* __restrict__ s, const float* __restrict__ g,
    const float* __restrict__ W_g1, const float* __restrict__ b_g1,
    const float* __restrict__ W_gh, const float* __restrict__ b_gh,
    const float* __restrict__ W_gc, const float* __restrict__ b_gc,
    const unsigned char* __restrict__ ws, float* __restrict__ out)
{
    const short* whT  = (const short*)(ws + WS_WHT);
    const short* b2T  = (const short*)(ws + WS_B2T);
    const short* ampd = (const short*)(ws + WS_AMPD);
    const float* c0v  = (const float*)(ws + WS_C0V);
    const float* dsv  = (const float*)(ws + WS_DSV);
    const float* bdf  = (const float*)(ws + WS_BDF);

    __shared__ unsigned char sp_l[260];   // bit b of sp_l[t] = s_pad[b][t]

    const int l   = threadIdx.x;   // 64
    const int n2  = l & 15;        // MFMA col / A-row
    const int q   = l >> 4;        // MFMA quad
    const int wgb = blockIdx.x * 2;

    // token staging: sp_l[t] = bits of s[:, t-1]; sp_l[0] = 0; pad 257..259 = 0
    for (int t = l; t < 260; t += 64) {
        unsigned v = 0;
        if (t >= 1 && t <= 256)
            v = (unsigned)(s[(wgb + 0) * 256 + t - 1] & 1) |
                ((unsigned)(s[(wgb + 1) * 256 + t - 1] & 1) << 1);
        sp_l[t] = (unsigned char)v;
    }

    // ---------- static fragments ----------
    bf16x8 Bf[16][2];
    #pragma unroll
    for (int tb = 0; tb < 16; ++tb) {
        const int n = tb * 16 + n2;
        #pragma unroll
        for (int kf = 0; kf < 2; ++kf)
            Bf[tb][kf] = *(const bf16x8*)(whT + n * 256 + kf * 32 + q * 8);
    }
    // Atv: tanh head, A-layout (m dup period 2 -> b = n2&1)
    bf16x8 Atv;
    {
        const float g_a = g[wgb + (n2 & 1)];
        #pragma unroll
        for (int j = 0; j < 8; ++j) {
            int k = q * 8 + j;
            Atv[j] = f2bf(tanhf(g_a * W_g1[k] + b_g1[k]));
        }
    }
    // C0[tile] = Atv @ B2 + (one-hot s=0 + const) fold
    f32x4 C0[16];
    {
        const f32x4 zero4 = {0.f, 0.f, 0.f, 0.f};
        #pragma unroll
        for (int tb = 0; tb < 16; ++tb) {
            bf16x8 b2f = *(const bf16x8*)(b2T + (tb * 16 + n2) * 32 + q * 8);
            C0[tb] = __builtin_amdgcn_mfma_f32_16x16x32_bf16(Atv, b2f, zero4, 0, 0, 0);
            float ca = c0v[tb * 16 + n2];
            #pragma unroll
            for (int r = 0; r < 4; ++r) C0[tb][r] += ca;
        }
    }
    // logit diff column (col 0 only)
    bf16x8 BLd0 = {0,0,0,0,0,0,0,0}, BLd1 = {0,0,0,0,0,0,0,0};
    f32x4 CL0 = {0.f, 0.f, 0.f, 0.f};
    if (n2 == 0) {
        BLd0 = *(const bf16x8*)(ampd + q * 8);
        BLd1 = *(const bf16x8*)(ampd + 32 + q * 8);
        float bd = bdf[0];
        CL0[0] = bd; CL0[1] = bd; CL0[2] = bd; CL0[3] = bd;
    }
    // per-lane s-delta for the 4 gates at owned f = l
    float Dsel4[4];
    #pragma unroll
    for (int gi = 0; gi < 4; ++gi) Dsel4[gi] = dsv[gi * 64 + l];

    // state init: c0/h0; hw = packed {bf16 h0[b=0], bf16 h0[b=1]} at f = l
    float cst[2];
    int hw;
    {
        float g0 = g[wgb + 0], g1 = g[wgb + 1];
        cst[0] = g0 * W_gc[l] + b_gc[l];
        cst[1] = g1 * W_gc[l] + b_gc[l];
        unsigned h0 = (unsigned short)f2bf(g0 * W_gh[l] + b_gh[l]);
        unsigned h1 = (unsigned short)f2bf(g1 * W_gh[l] + b_gh[l]);
        hw = (int)(h0 | (h1 << 16));
    }
    __syncthreads();   // sp_l visibility; none in the loop

    // ---------- recurrence: 257 steps, single wave, barrier-free ----------
    const bool mq1 = (q & 1) != 0, mq2 = (q & 2) != 0;
    const int baseA = q * 32;
    const unsigned selv = (n2 & 1) ? 0x07060302u : 0x05040100u;
    const f32x4 zero4 = {0.f, 0.f, 0.f, 0.f};
    float slp0 = 0.f, slp1 = 0.f;
    unsigned spt = 0;                                       // sp_l[0]

    for (int t = 0; t <= 256; ++t) {
        unsigned spt_n = sp_l[t + 1];      // prefetch, consumed next iter

        // A-frag rebuild from hw via single-stage bpermute crossbar
        int pA[8], pB[8];
        #pragma unroll
        for (int j = 0; j < 8; ++j) {
            pA[j] = __builtin_amdgcn_ds_bpermute(baseA + 4 * j, hw);
            pB[j] = __builtin_amdgcn_ds_bpermute(baseA + 128 + 4 * j, hw);
        }
        u32x4 a0u, a1u;
        #pragma unroll
        for (int d = 0; d < 4; ++d) {
            a0u[d] = __builtin_amdgcn_perm((unsigned)pA[2 * d + 1], (unsigned)pA[2 * d], selv);
            a1u[d] = __builtin_amdgcn_perm((unsigned)pB[2 * d + 1], (unsigned)pB[2 * d], selv);
        }
        bf16x8 a0 = __builtin_bit_cast(bf16x8, a0u);
        bf16x8 a1 = __builtin_bit_cast(bf16x8, a1u);

        // 34 INDEPENDENT MFMAs: no accumulator chaining anywhere
        f32x4 accA[16], accB[16];
        #pragma unroll
        for (int tb = 0; tb < 16; ++tb) {
            accA[tb] = __builtin_amdgcn_mfma_f32_16x16x32_bf16(a0, Bf[tb][0], C0[tb], 0, 0, 0);
            accB[tb] = __builtin_amdgcn_mfma_f32_16x16x32_bf16(a1, Bf[tb][1], zero4, 0, 0, 0);
        }
        f32x4 accLA = __builtin_amdgcn_mfma_f32_16x16x32_bf16(a0, BLd0, CL0, 0, 0, 0);
        f32x4 accLB = __builtin_amdgcn_mfma_f32_16x16x32_bf16(a1, BLd1, zero4, 0, 0, 0);

        const float fr0 = (float)(spt & 1u);
        const float fr1 = (float)((spt >> 1) & 1u);

        if (t >= 1) {   // log-prob of token s[:,t-1] (lane 0's values are used)
            #pragma unroll
            for (int r = 0; r < 2; ++r) {
                float d = accLA[r] + accLB[r];           // l1 - l0 for b=r
                float x = ((spt >> r) & 1u) ? -d : d;    // l_other - l_s
                float e = __builtin_amdgcn_exp2f(L2E * x);
                float sp = LN2 * __builtin_amdgcn_logf(1.0f + e);
                if (r == 0) slp0 -= sp; else slp1 -= sp;
            }
        }

        // extraction + gate math (t=256 computes dead h; harmless)
        float z[4][2];
        #pragma unroll
        for (int gi = 0; gi < 4; ++gi) {
            #pragma unroll
            for (int b = 0; b < 2; ++b) {
                float xA01 = mq1 ? accA[4 * gi + 1][b] : accA[4 * gi + 0][b];
                float xA23 = mq1 ? accA[4 * gi + 3][b] : accA[4 * gi + 2][b];
                float xB01 = mq1 ? accB[4 * gi + 1][b] : accB[4 * gi + 0][b];
                float xB23 = mq1 ? accB[4 * gi + 3][b] : accB[4 * gi + 2][b];
                float fr  = b ? fr1 : fr0;
                z[gi][b] = (mq2 ? xA23 : xA01) + (mq2 ? xB23 : xB01) + fr * Dsel4[gi];
            }
        }
        unsigned hparts[2];
        #pragma unroll
        for (int b = 0; b < 2; ++b) {
            float si = fsig(z[0][b]), sf = fsig(z[1][b]);
            float tg = ftanh(z[2][b]), so = fsig(z[3][b]);
            float c = sf * cst[b] + si * tg;
            cst[b] = c;
            hparts[b] = (unsigned short)f2bf(so * ftanh(c));
        }
        hw = (int)(hparts[0] | (hparts[1] << 16));
        spt = spt_n;
    }

    if (l == 0) {
        out[wgb + 0] = slp0;
        out[wgb + 1] = slp1;
    }
}

extern "C" void kernel_launch(void* const* d_in, const int* in_sizes, int n_in,
                              void* d_out, int out_size, void* d_ws, size_t ws_size,
                              hipStream_t stream) {
    (void)in_sizes; (void)n_in; (void)out_size; (void)ws_size;
    const int*   s      = (const int*)d_in[0];
    const float* g      = (const float*)d_in[1];
    const float* W_emb  = (const float*)d_in[2];
    const float* b_emb  = (const float*)d_in[3];
    const float* W_g1   = (const float*)d_in[4];
    const float* b_g1   = (const float*)d_in[5];
    const float* W_g2   = (const float*)d_in[6];
    const float* b_g2   = (const float*)d_in[7];
    const float* W_gh   = (const float*)d_in[8];
    const float* b_gh   = (const float*)d_in[9];
    const float* W_gc   = (const float*)d_in[10];
    const float* b_gc   = (const float*)d_in[11];
    const float* Wi     = (const float*)d_in[12];
    const float* Wh     = (const float*)d_in[13];
    const float* b_lstm = (const float*)d_in[14];
    const float* W_amp  = (const float*)d_in[15];
    const float* b_amp  = (const float*)d_in[16];
    float* out = (float*)d_out;
    unsigned char* ws = (unsigned char*)d_ws;

    setup_fold<<<34, 256, 0, stream>>>(W_emb, b_emb, W_g2, b_g2, Wi,
                                       b_lstm, W_amp, b_amp, ws);
    setup_tr<<<256, 256, 0, stream>>>(Wh, ws);
    lstm_kernel<<<1024, 64, 0, stream>>>(s, g, W_g1, b_g1, W_gh, b_gh,
                                         W_gc, b_gc, ws, out);
}